// Round 3
// baseline (12469.939 us; speedup 1.0000x reference)
//
#include <hip/hip_runtime.h>
#include <stdint.h>

// SingleBandLSTM: B=64, IN=16, H=512, T=1024, 2-layer LSTM, constant input per step.
// Fused software-pipelined persistent kernel: 64 blocks x 512 threads, each block
// owns 8 hidden units of layer-0 AND 8 of layer-1 (layer-1 lags one step).
// Per step: ONE flag wait + ONE flag add. Ring slot[t] = {h0[t], h1[t-1]} (bf16).
// Consumers: relaxed poll -> fence(acquire, agent) (buffer_inv) -> plain coalesced
// dwordx4 loads (L2-shared within XCD). Producers: relaxed agent (sc1 write-through)
// stores, drained by __syncthreads' vmcnt(0) before the relaxed flag add.
// (R2 lesson: per-lane atomic staging loads bypass L2 and don't coalesce -> ~8us/step.)

#define TSEQ 1024
#define HDIM 512
#define BATCH 64
#define RING 8
#define NBLK 64

typedef __attribute__((ext_vector_type(8))) short bf16x8;
typedef __attribute__((ext_vector_type(4))) float f32x4;
typedef __attribute__((ext_vector_type(4))) unsigned int u32x4;

__device__ __forceinline__ unsigned short f2bf(float f) {
  union { float f; unsigned u; } v; v.f = f;
  unsigned r = v.u + 0x7FFFu + ((v.u >> 16) & 1u);   // RNE
  return (unsigned short)(r >> 16);
}
__device__ __forceinline__ float bf2f(unsigned short s) {
  union { unsigned u; float f; } v; v.u = ((unsigned)s) << 16; return v.f;
}
__device__ __forceinline__ float sigm(float x) { return 1.0f / (1.0f + __expf(-x)); }
__device__ __forceinline__ float tanh_(float x) { return 1.0f - 2.0f / (__expf(2.0f * x) + 1.0f); }

__device__ __forceinline__ void flag_add(int* p) {
  __hip_atomic_fetch_add(p, 1, __ATOMIC_RELAXED, __HIP_MEMORY_SCOPE_AGENT);
}
__device__ __forceinline__ void flag_wait(int* p, int target) {
  while (__hip_atomic_load(p, __ATOMIC_RELAXED, __HIP_MEMORY_SCOPE_AGENT) < target)
    __builtin_amdgcn_s_sleep(1);
}

// 64KB global (bf16 [64][512] row-major) -> LDS, XOR swizzle ((row&7)<<4) on byte addr.
// PLAIN coalesced loads; caller issues fence(acquire,agent) first for coherence.
__device__ __forceinline__ void stage64k(char* lds, const unsigned short* src, int tid) {
  const u32x4* s = (const u32x4*)src;
  #pragma unroll
  for (int i = 0; i < 8; ++i) {
    int q = tid + i * 512;                       // 16B-quad index, 4096 total
    u32x4 v = s[q];
    int row = q >> 6, kb = (q & 63) << 4;
    *(u32x4*)(lds + row * 1024 + (kb ^ ((row & 7) << 4))) = v;
  }
}
__device__ __forceinline__ void zero64k(char* lds, int tid) {
  u32x4 z = {0u, 0u, 0u, 0u};
  #pragma unroll
  for (int i = 0; i < 8; ++i) {
    int q = tid + i * 512;
    int row = q >> 6, kb = (q & 63) << 4;
    *(u32x4*)(lds + row * 1024 + (kb ^ ((row & 7) << 4))) = z;
  }
}

// ---------------- precompute kernels ----------------
__global__ void k_fc_in(const float* __restrict__ x, const float* __restrict__ w_in,
                        const float* __restrict__ b_in, float* __restrict__ h_in) {
  int b = blockIdx.x;      // 64
  int j = threadIdx.x;     // 512
  float acc = b_in[j];
  #pragma unroll
  for (int i = 0; i < 16; ++i) acc += x[b * 16 + i] * w_in[j * 16 + i];
  h_in[b * HDIM + j] = acc;
}

__global__ __launch_bounds__(512, 1)
void k_xg0(const float* __restrict__ h_in, const float* __restrict__ w_ih0,
           const float* __restrict__ b_ih0, const float* __restrict__ b_hh0,
           float* __restrict__ xg0) {
  __shared__ float hbuf[64 * 516];
  __shared__ float wbuf[8 * 520];
  int r0 = blockIdx.x * 8;           // 256 blocks x 8 rows = 2048 gate rows
  int tid = threadIdx.x;
  for (int i = 0; i < 64; ++i) {
    int c = tid + i * 512;
    hbuf[(c >> 9) * 516 + (c & 511)] = h_in[c];
  }
  for (int i = 0; i < 8; ++i) {
    int c = tid + i * 512;
    wbuf[(c >> 9) * 520 + (c & 511)] = w_ih0[(size_t)r0 * HDIM + c];
  }
  __syncthreads();
  int b = tid >> 3, rl = tid & 7;
  float acc = 0.f;
  for (int k = 0; k < 512; ++k) acc += hbuf[b * 516 + k] * wbuf[rl * 520 + k];
  int r = r0 + rl;
  xg0[(size_t)b * 2048 + r] = acc + b_ih0[r] + b_hh0[r];
}

// ---------------- fused persistent recurrence kernel ----------------
__global__ __launch_bounds__(512, 1)
void lstm_persist(const float* __restrict__ w_hh0,
                  const float* __restrict__ w_ih1,
                  const float* __restrict__ w_hh1,
                  const float* __restrict__ b_ih1,
                  const float* __restrict__ b_hh1,
                  const float* __restrict__ w_out,
                  const float* __restrict__ b_out,
                  const float* __restrict__ xg0,
                  unsigned short* __restrict__ ring,   // RING slots x {h0, h1} x 64KB
                  int* __restrict__ flags,             // TSEQ+1 ready counters
                  float* __restrict__ out) {
  __shared__ __align__(16) unsigned short hA[BATCH * HDIM];  // h0[t-1], swizzled
  __shared__ __align__(16) unsigned short hB[BATCH * HDIM];  // h1[t-2], swizzled
  __shared__ float gbuf[BATCH * 68];                         // [batch][64 gate rows]
  __shared__ float wout_s[HDIM];
  char* hAc = (char*)hA;
  char* hBc = (char*)hB;

  const int tid = threadIdx.x;
  const int blk = blockIdx.x;          // 0..63
  const int u0 = blk * 8;              // owned unit base (both layers)

  const int wave = tid >> 6, lane = tid & 63;
  const int nt = wave & 3;             // 0,1 = L0 row-tiles; 2,3 = L1 row-tiles
  const int mh = wave >> 2;            // batch half (0: b0-31, 1: b32-63)
  const int ln15 = lane & 15, lg = lane >> 4;
  const bool isL1w = (nt >= 2);

  const int n_local = nt * 16 + ln15;  // 0..63 (0-31 L0 rows, 32-63 L1 rows)
  const int rl = n_local & 31;         // unit_local*4 + gate
  const int grow = (rl & 3) * HDIM + u0 + (rl >> 2);  // row in the 4H weight matrix

  wout_s[tid] = w_out[tid];
  const float bout = b_out[0];

  // ---- weight fragments into registers (fp32 -> bf16) ----
  // pass1 B (A = h0 tile): wh0 for L0 waves, wi1 for L1 waves.
  // pass2 B (A = h1 tile): wh1, L1 waves only.
  bf16x8 wA[16], wB[16];
  {
    const float* W1 = (isL1w ? w_ih1 : w_hh0) + (size_t)grow * HDIM;
    #pragma unroll
    for (int kt = 0; kt < 16; ++kt) {
      const float* s = W1 + kt * 32 + lg * 8;
      bf16x8 r;
      #pragma unroll
      for (int e = 0; e < 8; ++e) r[e] = (short)f2bf(s[e]);
      wA[kt] = r;
    }
  }
  if (isL1w) {
    const float* W2 = w_hh1 + (size_t)grow * HDIM;
    #pragma unroll
    for (int kt = 0; kt < 16; ++kt) {
      const float* s = W2 + kt * 32 + lg * 8;
      bf16x8 r;
      #pragma unroll
      for (int e = 0; e < 8; ++e) r[e] = (short)f2bf(s[e]);
      wB[kt] = r;
    }
  }

  // ---- accumulator init (xg0 fragment for L0 waves; L1 bias for L1 waves) ----
  f32x4 init0, init1;
  if (!isL1w) {
    #pragma unroll
    for (int r = 0; r < 4; ++r) {
      init0[r] = xg0[(size_t)(mh * 32 + lg * 4 + r) * 2048 + grow];
      init1[r] = xg0[(size_t)(mh * 32 + 16 + lg * 4 + r) * 2048 + grow];
    }
  } else {
    float bv = b_ih1[grow] + b_hh1[grow];
    #pragma unroll
    for (int r = 0; r < 4; ++r) { init0[r] = bv; init1[r] = bv; }
  }

  // cell states: this thread owns (batch bc, unit u0+uc) in BOTH layers
  float c0 = 0.f, c1 = 0.f;
  const int bc = tid >> 3, uc = tid & 7;

  const int r0 = mh * 32 + ln15, r1 = r0 + 16;
  const int xs = (r0 & 7) << 4;        // (r1&7)==(r0&7)

  // out-dot assignment (threads 0..255, i.e. waves 0-3 = light L0 waves)
  const int ob = tid >> 2, oseg = tid & 3;
  const int oxs = (ob & 7) << 4;

  const size_t SLOT = (size_t)2 * BATCH * HDIM;

  for (int t = 0; t <= TSEQ; ++t) {
    // ---- phase 1: wait + stage slot[t-1] = {h0[t-1], h1[t-2]} ----
    if (t > 0) {
      if (tid == 0) flag_wait(&flags[t - 1], NBLK);
      __syncthreads();
      __builtin_amdgcn_fence(__ATOMIC_ACQUIRE, "agent");   // buffer_inv: fresh L2
      const unsigned short* slot = ring + (size_t)((t - 1) & (RING - 1)) * SLOT;
      stage64k(hAc, slot, tid);
      stage64k(hBc, slot + BATCH * HDIM, tid);
    } else {
      zero64k(hAc, tid);
      zero64k(hBc, tid);
    }
    __syncthreads();

    // ---- phase 2: MFMA (L0 waves: hh0 over hA; L1 waves: ih1 over hA + hh1 over hB) ----
    if (!isL1w) {
      if (t < TSEQ) {
        f32x4 a0 = init0, a1 = init1;
        #pragma unroll
        for (int kt = 0; kt < 16; ++kt) {
          const int kb = kt * 64 + lg * 16;
          bf16x8 hA0 = *(const bf16x8*)(hAc + r0 * 1024 + (kb ^ xs));
          bf16x8 hA1 = *(const bf16x8*)(hAc + r1 * 1024 + (kb ^ xs));
          a0 = __builtin_amdgcn_mfma_f32_16x16x32_bf16(hA0, wA[kt], a0, 0, 0, 0);
          a1 = __builtin_amdgcn_mfma_f32_16x16x32_bf16(hA1, wA[kt], a1, 0, 0, 0);
        }
        #pragma unroll
        for (int r = 0; r < 4; ++r) {
          gbuf[(mh * 32 + lg * 4 + r) * 68 + n_local] = a0[r];
          gbuf[(mh * 32 + 16 + lg * 4 + r) * 68 + n_local] = a1[r];
        }
      }
    } else {
      if (t >= 1) {
        f32x4 a0 = init0, a1 = init1;
        f32x4 d0 = {0.f, 0.f, 0.f, 0.f}, d1 = {0.f, 0.f, 0.f, 0.f};
        #pragma unroll
        for (int kt = 0; kt < 16; ++kt) {
          const int kb = kt * 64 + lg * 16;
          bf16x8 iA0 = *(const bf16x8*)(hAc + r0 * 1024 + (kb ^ xs));
          bf16x8 iA1 = *(const bf16x8*)(hAc + r1 * 1024 + (kb ^ xs));
          bf16x8 iB0 = *(const bf16x8*)(hBc + r0 * 1024 + (kb ^ xs));
          bf16x8 iB1 = *(const bf16x8*)(hBc + r1 * 1024 + (kb ^ xs));
          a0 = __builtin_amdgcn_mfma_f32_16x16x32_bf16(iA0, wA[kt], a0, 0, 0, 0);
          a1 = __builtin_amdgcn_mfma_f32_16x16x32_bf16(iA1, wA[kt], a1, 0, 0, 0);
          d0 = __builtin_amdgcn_mfma_f32_16x16x32_bf16(iB0, wB[kt], d0, 0, 0, 0);
          d1 = __builtin_amdgcn_mfma_f32_16x16x32_bf16(iB1, wB[kt], d1, 0, 0, 0);
        }
        a0 += d0; a1 += d1;
        #pragma unroll
        for (int r = 0; r < 4; ++r) {
          gbuf[(mh * 32 + lg * 4 + r) * 68 + n_local] = a0[r];
          gbuf[(mh * 32 + 16 + lg * 4 + r) * 68 + n_local] = a1[r];
        }
      }
    }

    // ---- out[:, t-2] from staged h1[t-2] tile (threads 0-255, light waves) ----
    if (t >= 2 && tid < 256) {
      float od = 0.f;
      #pragma unroll
      for (int j = 0; j < 16; ++j) {
        const int kb = (j * 4 + oseg) * 16;   // interleaved 16B chunks
        bf16x8 hv = *(const bf16x8*)(hBc + ob * 1024 + (kb ^ oxs));
        const float* wo = &wout_s[kb >> 1];
        #pragma unroll
        for (int e = 0; e < 8; ++e) od += bf2f((unsigned short)hv[e]) * wo[e];
      }
      od += __shfl_xor(od, 1);
      od += __shfl_xor(od, 2);
      if (oseg == 0) out[ob * TSEQ + (t - 2)] = od + bout;
    }
    __syncthreads();

    // ---- phase 3: nonlinearity + publish slot[t] = {h0[t], h1[t-1]} ----
    unsigned short h0u = 0, h1u = 0;
    if (t < TSEQ) {
      f32x4 g = *(const f32x4*)&gbuf[bc * 68 + uc * 4];
      float ii = sigm(g[0]), ff = sigm(g[1]), zz = tanh_(g[2]), oo = sigm(g[3]);
      c0 = ff * c0 + ii * zz;
      h0u = f2bf(oo * tanh_(c0));
    }
    if (t >= 1) {
      f32x4 g = *(const f32x4*)&gbuf[bc * 68 + 32 + uc * 4];
      float ii = sigm(g[0]), ff = sigm(g[1]), zz = tanh_(g[2]), oo = sigm(g[3]);
      c1 = ff * c1 + ii * zz;
      h1u = f2bf(oo * tanh_(c1));
    }
    {
      unsigned short p0 = (unsigned short)__shfl_xor((int)h0u, 1);
      unsigned short p1 = (unsigned short)__shfl_xor((int)h1u, 1);
      if ((tid & 1) == 0) {
        unsigned short* slotw = ring + (size_t)(t & (RING - 1)) * SLOT;
        unsigned w0 = (unsigned)h0u | ((unsigned)p0 << 16);
        unsigned w1 = (unsigned)h1u | ((unsigned)p1 << 16);
        __hip_atomic_store((unsigned*)(slotw + bc * HDIM + u0 + uc), w0,
                           __ATOMIC_RELAXED, __HIP_MEMORY_SCOPE_AGENT);
        __hip_atomic_store((unsigned*)(slotw + BATCH * HDIM + bc * HDIM + u0 + uc), w1,
                           __ATOMIC_RELAXED, __HIP_MEMORY_SCOPE_AGENT);
      }
    }
    __syncthreads();   // implicit vmcnt(0): sc1 stores visible at coherent point
    if (tid == 0) flag_add(&flags[t]);
  }

  // ---- epilogue: out[:, T-1] from h1[T-1] in slot[TSEQ] ----
  if (tid == 0) flag_wait(&flags[TSEQ], NBLK);
  __syncthreads();
  __builtin_amdgcn_fence(__ATOMIC_ACQUIRE, "agent");
  stage64k(hBc, ring + (size_t)(TSEQ & (RING - 1)) * SLOT + BATCH * HDIM, tid);
  __syncthreads();
  if (tid < 256) {
    float od = 0.f;
    #pragma unroll
    for (int j = 0; j < 16; ++j) {
      const int kb = (j * 4 + oseg) * 16;
      bf16x8 hv = *(const bf16x8*)(hBc + ob * 1024 + (kb ^ oxs));
      const float* wo = &wout_s[kb >> 1];
      #pragma unroll
      for (int e = 0; e < 8; ++e) od += bf2f((unsigned short)hv[e]) * wo[e];
    }
    od += __shfl_xor(od, 1);
    od += __shfl_xor(od, 2);
    if (oseg == 0) out[ob * TSEQ + (TSEQ - 1)] = od + bout;
  }
}

extern "C" void kernel_launch(void* const* d_in, const int* in_sizes, int n_in,
                              void* d_out, int out_size, void* d_ws, size_t ws_size,
                              hipStream_t stream) {
  (void)in_sizes; (void)n_in; (void)out_size; (void)ws_size;
  const float* x     = (const float*)d_in[0];
  const float* w_in  = (const float*)d_in[1];
  const float* b_in  = (const float*)d_in[2];
  const float* w_ih0 = (const float*)d_in[3];
  const float* w_hh0 = (const float*)d_in[4];
  const float* b_ih0 = (const float*)d_in[5];
  const float* b_hh0 = (const float*)d_in[6];
  const float* w_ih1 = (const float*)d_in[7];
  const float* w_hh1 = (const float*)d_in[8];
  const float* b_ih1 = (const float*)d_in[9];
  const float* b_hh1 = (const float*)d_in[10];
  const float* w_out = (const float*)d_in[11];
  const float* b_out = (const float*)d_in[12];

  char* ws = (char*)d_ws;
  unsigned short* ring = (unsigned short*)(ws + 0);             // 8 * 128KB = 1MB
  float* xg0  = (float*)(ws + 1048576);                         // 512KB
  float* h_in = (float*)(ws + 1572864);                         // 128KB
  int*   flags = (int*)(ws + 1703936);                          // (TSEQ+1)*4

  hipMemsetAsync(flags, 0, (TSEQ + 1) * sizeof(int), stream);
  k_fc_in<<<64, 512, 0, stream>>>(x, w_in, b_in, h_in);
  k_xg0<<<256, 512, 0, stream>>>(h_in, w_ih0, b_ih0, b_hh0, xg0);
  lstm_persist<<<NBLK, 512, 0, stream>>>(w_hh0, w_ih1, w_hh1, b_ih1, b_hh1,
                                         w_out, b_out, xg0, ring,
                                         flags, (float*)d_out);
}

// Round 5
// 10861.448 us; speedup vs baseline: 1.1481x; 1.1481x over previous
//
#include <hip/hip_runtime.h>
#include <stdint.h>

// SingleBandLSTM: B=64, IN=16, H=512, T=1024, 2-layer LSTM, constant input per step.
// Split persistent design: 64 blocks x 512 threads. Even blocks: layer-0 recurrence
// (xg0 precomputed, folded into MFMA init). Odd blocks: layer-1 (ih from h0[s], hh
// from h1[s-1]) + output dot. L0 runs ahead of L1 (ring0 depth 16, backpressure
// check every 8 steps).
//
// Sync protocol (LLC/agent-coherent, zero RMW, zero cache-maintenance ops):
//  - ring layout slice-contiguous: [slot][producer block][batch][16 units bf16]
//    -> publish = wave 0, lane b stores its 32B batch-slice via 4x u64 relaxed
//       agent atomics (global_store_dwordx2 sc1, coalesced, LLC-visible)
//  - data-before-flag: bare `s_waitcnt vmcnt(0)` asm (no outputs!) after data
//    stores, then lane 0 plain relaxed-agent flag store flags[blk] = t+1
//  - waiters: wave 0 polls all 32 seq words with one 32-lane relaxed load + __all
//  - staging: u64 relaxed-agent atomic loads (compiler-generated -> correct
//    waitcnt insertion; R4 lesson: NEVER feed inline-asm load outputs to
//    compiler-generated consumers), swizzled LDS writes.
// R3 lessons kept: no buffer_inv (L2 thrash), no counter atomics, no layer lockstep.

#define TSEQ 1024
#define HDIM 512
#define BATCH 64
#define R0D 16   // h0 ring depth (slots)
#define R1D 8    // h1 ring depth

typedef __attribute__((ext_vector_type(8))) short bf16x8;
typedef __attribute__((ext_vector_type(4))) float f32x4;
typedef __attribute__((ext_vector_type(4))) unsigned int u32x4;
typedef unsigned long long u64;

__device__ __forceinline__ unsigned short f2bf(float f) {
  union { float f; unsigned u; } v; v.f = f;
  unsigned r = v.u + 0x7FFFu + ((v.u >> 16) & 1u);   // RNE
  return (unsigned short)(r >> 16);
}
__device__ __forceinline__ float bf2f(unsigned short s) {
  union { unsigned u; float f; } v; v.u = ((unsigned)s) << 16; return v.f;
}
__device__ __forceinline__ float sigm(float x) { return 1.0f / (1.0f + __expf(-x)); }
__device__ __forceinline__ float tanh_(float x) { return 1.0f - 2.0f / (__expf(2.0f * x) + 1.0f); }

__device__ __forceinline__ u64 g_ld64(const u64* p) {
  return __hip_atomic_load(p, __ATOMIC_RELAXED, __HIP_MEMORY_SCOPE_AGENT);
}
__device__ __forceinline__ void g_st64(u64* p, u64 v) {
  __hip_atomic_store(p, v, __ATOMIC_RELAXED, __HIP_MEMORY_SCOPE_AGENT);
}
__device__ __forceinline__ int g_ld32(const int* p) {
  return __hip_atomic_load(p, __ATOMIC_RELAXED, __HIP_MEMORY_SCOPE_AGENT);
}
__device__ __forceinline__ void g_st32(int* p, int v) {
  __hip_atomic_store(p, v, __ATOMIC_RELAXED, __HIP_MEMORY_SCOPE_AGENT);
}

// Poll: lanes read flags[lane&31]; pass when every entry >= target.
__device__ __forceinline__ void poll_ge(const int* f, int tgt, int lane) {
  const int* a = f + (lane & 31);
  while (!__all(g_ld32(a) >= tgt)) __builtin_amdgcn_s_sleep(1);
}
__device__ __forceinline__ void poll2_ge(const int* fa, int ta, const int* fb, int tb, int lane) {
  const int* pa = fa + (lane & 31);
  const int* pb = fb + (lane & 31);
  while (true) {
    int va = g_ld32(pa);
    int vb = g_ld32(pb);
    if (__all((va >= ta) && (vb >= tb))) break;
    __builtin_amdgcn_s_sleep(1);
  }
}

// Stage 64KB ring slot [32 srcblk][64 b][32B] -> LDS [b][512 units bf16], XOR
// swizzle ((b&7)<<4) on byte col. q indexes 16B quads; quad q -> producer q>>7,
// batch (q>>1)&63, unit-half q&1.
__device__ __forceinline__ void stage64(char* lds, const char* src, int tid) {
  u64 lo[8], hi[8];
  #pragma unroll
  for (int i = 0; i < 8; ++i) {
    const u64* s = (const u64*)(src + (size_t)(tid + i * 512) * 16);
    lo[i] = g_ld64(s);
    hi[i] = g_ld64(s + 1);
  }
  #pragma unroll
  for (int i = 0; i < 8; ++i) {
    int q = tid + i * 512;
    int b = (q >> 1) & 63;
    int colb = ((q >> 7) << 5) | ((q & 1) << 4);
    u32x4 v;
    ((u64*)&v)[0] = lo[i];
    ((u64*)&v)[1] = hi[i];
    *(u32x4*)(lds + b * 1024 + (colb ^ ((b & 7) << 4))) = v;
  }
}
__device__ __forceinline__ void stage64x2(char* ldsA, const char* srcA,
                                          char* ldsB, const char* srcB, int tid) {
  u64 la[8], ha[8], lb[8], hb[8];
  #pragma unroll
  for (int i = 0; i < 8; ++i) {
    const u64* sa = (const u64*)(srcA + (size_t)(tid + i * 512) * 16);
    la[i] = g_ld64(sa);
    ha[i] = g_ld64(sa + 1);
  }
  #pragma unroll
  for (int i = 0; i < 8; ++i) {
    const u64* sb = (const u64*)(srcB + (size_t)(tid + i * 512) * 16);
    lb[i] = g_ld64(sb);
    hb[i] = g_ld64(sb + 1);
  }
  #pragma unroll
  for (int i = 0; i < 8; ++i) {
    int q = tid + i * 512;
    int b = (q >> 1) & 63;
    int colb = ((q >> 7) << 5) | ((q & 1) << 4);
    int off = b * 1024 + (colb ^ ((b & 7) << 4));
    u32x4 va, vb;
    ((u64*)&va)[0] = la[i]; ((u64*)&va)[1] = ha[i];
    ((u64*)&vb)[0] = lb[i]; ((u64*)&vb)[1] = hb[i];
    *(u32x4*)(ldsA + off) = va;
    *(u32x4*)(ldsB + off) = vb;
  }
}
__device__ __forceinline__ void zerobuf(char* lds, int tid) {
  u32x4 z = {0u, 0u, 0u, 0u};
  #pragma unroll
  for (int i = 0; i < 8; ++i)
    *(u32x4*)(lds + (size_t)(tid + i * 512) * 16) = z;
}

// Publish this block's 2KB slice (wave 0 only): lane b stores 32B, drain, flag.
__device__ __forceinline__ void publish(char* ringslot, int p, const unsigned short* hpk,
                                        int lane, int* flag, int val) {
  const u64* s = (const u64*)((const char*)hpk + lane * 32);   // LDS
  u64* d = (u64*)(ringslot + p * 2048 + lane * 32);
  u64 v0 = s[0], v1 = s[1], v2 = s[2], v3 = s[3];
  g_st64(d + 0, v0);
  g_st64(d + 1, v1);
  g_st64(d + 2, v2);
  g_st64(d + 3, v3);
  asm volatile("s_waitcnt vmcnt(0)" ::: "memory");   // data ack'd at LLC before flag
  if (lane == 0) g_st32(flag, val);
}

// ---------------- precompute kernels ----------------
__global__ void k_fc_in(const float* __restrict__ x, const float* __restrict__ w_in,
                        const float* __restrict__ b_in, float* __restrict__ h_in) {
  int b = blockIdx.x;      // 64
  int j = threadIdx.x;     // 512
  float acc = b_in[j];
  #pragma unroll
  for (int i = 0; i < 16; ++i) acc += x[b * 16 + i] * w_in[j * 16 + i];
  h_in[b * HDIM + j] = acc;
}

__global__ __launch_bounds__(512, 1)
void k_xg0(const float* __restrict__ h_in, const float* __restrict__ w_ih0,
           const float* __restrict__ b_ih0, const float* __restrict__ b_hh0,
           float* __restrict__ xg0) {
  __shared__ float hbuf[64 * 516];
  __shared__ float wbuf[8 * 520];
  int r0 = blockIdx.x * 8;           // 256 blocks x 8 rows = 2048 gate rows
  int tid = threadIdx.x;
  for (int i = 0; i < 64; ++i) {
    int c = tid + i * 512;
    hbuf[(c >> 9) * 516 + (c & 511)] = h_in[c];
  }
  for (int i = 0; i < 8; ++i) {
    int c = tid + i * 512;
    wbuf[(c >> 9) * 520 + (c & 511)] = w_ih0[(size_t)r0 * HDIM + c];
  }
  __syncthreads();
  int b = tid >> 3, rl = tid & 7;
  float acc = 0.f;
  for (int k = 0; k < 512; ++k) acc += hbuf[b * 516 + k] * wbuf[rl * 520 + k];
  int r = r0 + rl;
  xg0[(size_t)b * 2048 + r] = acc + b_ih0[r] + b_hh0[r];
}

// ---------------- persistent recurrence kernel ----------------
__global__ __launch_bounds__(512, 1)
void lstm_persist(const float* __restrict__ w_hh0,
                  const float* __restrict__ w_ih1,
                  const float* __restrict__ w_hh1,
                  const float* __restrict__ b_ih1,
                  const float* __restrict__ b_hh1,
                  const float* __restrict__ w_out,
                  const float* __restrict__ b_out,
                  const float* __restrict__ xg0,
                  unsigned short* __restrict__ ring0,
                  unsigned short* __restrict__ ring1,
                  int* __restrict__ flags,
                  float* __restrict__ out) {
  __shared__ __align__(16) unsigned short hA[BATCH * HDIM];  // 64KB swizzled
  __shared__ __align__(16) unsigned short hB[BATCH * HDIM];  // 64KB swizzled (L1 only)
  __shared__ float gbuf[BATCH * 68];
  __shared__ __align__(16) unsigned short hpk[BATCH * 16];   // packed h slice (2KB)
  __shared__ float wout_s[HDIM];
  char* hAc = (char*)hA;
  char* hBc = (char*)hB;

  const int tid = threadIdx.x;
  const int blk = blockIdx.x;
  const int layer = blk & 1;          // even = L0, odd = L1 (XCD balance)
  const int p = blk >> 1;             // 0..31 within layer group
  const int u0 = p * 16;

  const int wave = tid >> 6, lane = tid & 63;
  const int nt = wave & 3, mh = wave >> 2;
  const int ln15 = lane & 15, lg = lane >> 4;

  const int n_local = nt * 16 + ln15;                          // 0..63 gate-row local
  const int grow = (n_local & 3) * HDIM + u0 + (n_local >> 2); // global gate row

  int* f0 = flags;        // 32 seq words, layer-0 producers
  int* f1 = flags + 32;   // 32 seq words, layer-1 producers

  wout_s[tid] = w_out[tid];
  const float bout = b_out[0];

  // ---- weight fragments (fp32 -> bf16) ----
  bf16x8 wA[16], wB[16];
  {
    const float* W1 = (layer ? w_ih1 : w_hh0) + (size_t)grow * HDIM;
    #pragma unroll
    for (int kt = 0; kt < 16; ++kt) {
      const float* s = W1 + kt * 32 + lg * 8;
      bf16x8 r;
      #pragma unroll
      for (int e = 0; e < 8; ++e) r[e] = (short)f2bf(s[e]);
      wA[kt] = r;
    }
  }
  if (layer) {
    const float* W2 = w_hh1 + (size_t)grow * HDIM;
    #pragma unroll
    for (int kt = 0; kt < 16; ++kt) {
      const float* s = W2 + kt * 32 + lg * 8;
      bf16x8 r;
      #pragma unroll
      for (int e = 0; e < 8; ++e) r[e] = (short)f2bf(s[e]);
      wB[kt] = r;
    }
  }

  // ---- accumulator init ----
  f32x4 init0, init1;
  if (!layer) {
    #pragma unroll
    for (int r = 0; r < 4; ++r) {
      init0[r] = xg0[(size_t)(mh * 32 + lg * 4 + r) * 2048 + grow];
      init1[r] = xg0[(size_t)(mh * 32 + 16 + lg * 4 + r) * 2048 + grow];
    }
  } else {
    float bv = b_ih1[grow] + b_hh1[grow];
    #pragma unroll
    for (int r = 0; r < 4; ++r) { init0[r] = bv; init1[r] = bv; }
  }

  float cs0 = 0.f, cs1 = 0.f;          // cell states for (pb, pu), (pb, pu+1)
  const int pb = tid >> 3;
  const int pu = (tid << 1) & 15;

  const int r0 = mh * 32 + ln15, r1 = r0 + 16;
  const int xs = (r0 & 7) << 4;

  const int ob = tid >> 2, oseg = tid & 3;   // out-dot (L1, tid<256)
  const int oxs = (ob & 7) << 4;

  const size_t SL = (size_t)BATCH * HDIM;    // 32768 elems = 64KB

  if (!layer) {
    // ================= layer 0 =================
    for (int t = 0; t < TSEQ; ++t) {
      if (wave == 0) {
        if (t > 0) poll_ge(f0, t, lane);                       // h0[t-1] published
        if (t >= 16 && (t & 7) == 0) poll_ge(f1, t - 8, lane); // ring0 backpressure
      }
      __syncthreads();
      if (t > 0) stage64(hAc, (const char*)(ring0 + (size_t)((t - 1) & (R0D - 1)) * SL), tid);
      else       zerobuf(hAc, tid);
      __syncthreads();

      f32x4 a0 = init0, a1 = init1;
      #pragma unroll
      for (int kt = 0; kt < 16; ++kt) {
        const int kb = kt * 64 + lg * 16;
        bf16x8 h0 = *(const bf16x8*)(hAc + r0 * 1024 + (kb ^ xs));
        bf16x8 h1 = *(const bf16x8*)(hAc + r1 * 1024 + (kb ^ xs));
        a0 = __builtin_amdgcn_mfma_f32_16x16x32_bf16(h0, wA[kt], a0, 0, 0, 0);
        a1 = __builtin_amdgcn_mfma_f32_16x16x32_bf16(h1, wA[kt], a1, 0, 0, 0);
      }
      #pragma unroll
      for (int r = 0; r < 4; ++r) {
        gbuf[(mh * 32 + lg * 4 + r) * 68 + n_local] = a0[r];
        gbuf[(mh * 32 + 16 + lg * 4 + r) * 68 + n_local] = a1[r];
      }
      __syncthreads();

      {
        f32x4 gA = *(const f32x4*)&gbuf[pb * 68 + pu * 4];
        f32x4 gB = *(const f32x4*)&gbuf[pb * 68 + pu * 4 + 4];
        float i0 = sigm(gA[0]), ff0 = sigm(gA[1]), z0 = tanh_(gA[2]), o0 = sigm(gA[3]);
        float i1 = sigm(gB[0]), ff1 = sigm(gB[1]), z1 = tanh_(gB[2]), o1 = sigm(gB[3]);
        cs0 = ff0 * cs0 + i0 * z0;
        cs1 = ff1 * cs1 + i1 * z1;
        unsigned pk = (unsigned)f2bf(o0 * tanh_(cs0)) | ((unsigned)f2bf(o1 * tanh_(cs1)) << 16);
        *(unsigned*)&hpk[pb * 16 + pu] = pk;
      }
      __syncthreads();
      if (wave == 0)
        publish((char*)(ring0 + (size_t)(t & (R0D - 1)) * SL), p, hpk, lane, &f0[p], t + 1);
    }
  } else {
    // ================= layer 1 =================
    for (int s = 0; s < TSEQ; ++s) {
      if (wave == 0) {
        if (s > 0) poll2_ge(f0, s + 1, f1, s, lane);   // h0[s] and h1[s-1]
        else       poll_ge(f0, 1, lane);
      }
      __syncthreads();
      if (s > 0) {
        stage64x2(hAc, (const char*)(ring0 + (size_t)(s & (R0D - 1)) * SL),
                  hBc, (const char*)(ring1 + (size_t)((s - 1) & (R1D - 1)) * SL), tid);
      } else {
        stage64(hAc, (const char*)(ring0 + 0), tid);
        zerobuf(hBc, tid);
      }
      __syncthreads();

      f32x4 a0 = init0, a1 = init1;
      f32x4 d0 = {0.f, 0.f, 0.f, 0.f}, d1 = {0.f, 0.f, 0.f, 0.f};
      #pragma unroll
      for (int kt = 0; kt < 16; ++kt) {
        const int kb = kt * 64 + lg * 16;
        bf16x8 iA0 = *(const bf16x8*)(hAc + r0 * 1024 + (kb ^ xs));
        bf16x8 iA1 = *(const bf16x8*)(hAc + r1 * 1024 + (kb ^ xs));
        bf16x8 iB0 = *(const bf16x8*)(hBc + r0 * 1024 + (kb ^ xs));
        bf16x8 iB1 = *(const bf16x8*)(hBc + r1 * 1024 + (kb ^ xs));
        a0 = __builtin_amdgcn_mfma_f32_16x16x32_bf16(iA0, wA[kt], a0, 0, 0, 0);
        a1 = __builtin_amdgcn_mfma_f32_16x16x32_bf16(iA1, wA[kt], a1, 0, 0, 0);
        d0 = __builtin_amdgcn_mfma_f32_16x16x32_bf16(iB0, wB[kt], d0, 0, 0, 0);
        d1 = __builtin_amdgcn_mfma_f32_16x16x32_bf16(iB1, wB[kt], d1, 0, 0, 0);
      }
      a0 += d0; a1 += d1;
      #pragma unroll
      for (int r = 0; r < 4; ++r) {
        gbuf[(mh * 32 + lg * 4 + r) * 68 + n_local] = a0[r];
        gbuf[(mh * 32 + 16 + lg * 4 + r) * 68 + n_local] = a1[r];
      }

      // out[:, s-1] from hB = h1[s-1] (redundant across L1 blocks; same value)
      if (s >= 1 && tid < 256) {
        float od = 0.f;
        #pragma unroll
        for (int j = 0; j < 16; ++j) {
          const int kb = (j * 4 + oseg) * 16;
          bf16x8 hv = *(const bf16x8*)(hBc + ob * 1024 + (kb ^ oxs));
          const float* wo = &wout_s[kb >> 1];
          #pragma unroll
          for (int e = 0; e < 8; ++e) od += bf2f((unsigned short)hv[e]) * wo[e];
        }
        od += __shfl_xor(od, 1);
        od += __shfl_xor(od, 2);
        if (oseg == 0) out[ob * TSEQ + (s - 1)] = od + bout;
      }
      __syncthreads();

      {
        f32x4 gA = *(const f32x4*)&gbuf[pb * 68 + pu * 4];
        f32x4 gB = *(const f32x4*)&gbuf[pb * 68 + pu * 4 + 4];
        float i0 = sigm(gA[0]), ff0 = sigm(gA[1]), z0 = tanh_(gA[2]), o0 = sigm(gA[3]);
        float i1 = sigm(gB[0]), ff1 = sigm(gB[1]), z1 = tanh_(gB[2]), o1 = sigm(gB[3]);
        cs0 = ff0 * cs0 + i0 * z0;
        cs1 = ff1 * cs1 + i1 * z1;
        unsigned pk = (unsigned)f2bf(o0 * tanh_(cs0)) | ((unsigned)f2bf(o1 * tanh_(cs1)) << 16);
        *(unsigned*)&hpk[pb * 16 + pu] = pk;
      }
      __syncthreads();
      if (wave == 0)
        publish((char*)(ring1 + (size_t)(s & (R1D - 1)) * SL), p, hpk, lane, &f1[p], s + 1);
    }
    // epilogue: out[:, T-1]
    if (wave == 0) poll_ge(f1, TSEQ, lane);
    __syncthreads();
    stage64(hBc, (const char*)(ring1 + (size_t)((TSEQ - 1) & (R1D - 1)) * SL), tid);
    __syncthreads();
    if (tid < 256) {
      float od = 0.f;
      #pragma unroll
      for (int j = 0; j < 16; ++j) {
        const int kb = (j * 4 + oseg) * 16;
        bf16x8 hv = *(const bf16x8*)(hBc + ob * 1024 + (kb ^ oxs));
        const float* wo = &wout_s[kb >> 1];
        #pragma unroll
        for (int e = 0; e < 8; ++e) od += bf2f((unsigned short)hv[e]) * wo[e];
      }
      od += __shfl_xor(od, 1);
      od += __shfl_xor(od, 2);
      if (oseg == 0) out[ob * TSEQ + (TSEQ - 1)] = od + bout;
    }
  }
}

extern "C" void kernel_launch(void* const* d_in, const int* in_sizes, int n_in,
                              void* d_out, int out_size, void* d_ws, size_t ws_size,
                              hipStream_t stream) {
  (void)in_sizes; (void)n_in; (void)out_size; (void)ws_size;
  const float* x     = (const float*)d_in[0];
  const float* w_in  = (const float*)d_in[1];
  const float* b_in  = (const float*)d_in[2];
  const float* w_ih0 = (const float*)d_in[3];
  const float* w_hh0 = (const float*)d_in[4];
  const float* b_ih0 = (const float*)d_in[5];
  const float* b_hh0 = (const float*)d_in[6];
  const float* w_ih1 = (const float*)d_in[7];
  const float* w_hh1 = (const float*)d_in[8];
  const float* b_ih1 = (const float*)d_in[9];
  const float* b_hh1 = (const float*)d_in[10];
  const float* w_out = (const float*)d_in[11];
  const float* b_out = (const float*)d_in[12];

  char* ws = (char*)d_ws;
  unsigned short* ring0 = (unsigned short*)(ws + 0);            // 16 * 64KB = 1MB
  unsigned short* ring1 = (unsigned short*)(ws + 1048576);      // 8 * 64KB = 512KB
  float* xg0   = (float*)(ws + 1572864);                        // 512KB
  float* h_in  = (float*)(ws + 2097152);                        // 128KB
  int*   flags = (int*)(ws + 2228224);                          // 64 ints

  hipMemsetAsync(flags, 0, 64 * sizeof(int), stream);
  k_fc_in<<<64, 512, 0, stream>>>(x, w_in, b_in, h_in);
  k_xg0<<<256, 512, 0, stream>>>(h_in, w_ih0, b_ih0, b_hh0, xg0);
  lstm_persist<<<64, 512, 0, stream>>>(w_hh0, w_ih1, w_hh1, b_ih1, b_hh1,
                                       w_out, b_out, xg0, ring0, ring1,
                                       flags, (float*)d_out);
}